// Round 18
// baseline (63.894 us; speedup 1.0000x reference)
//
#include <hip/hip_runtime.h>
#include <hip/hip_bf16.h>

// NeRF surrogate renderer, MI355X — round 18: max-residency config.
// R15's T-split failed because 4-wave blocks kept effective residency at 16
// waves/CU. Fix: 8-wave blocks + T-split(x2) + 1-SAMPLE chunks:
//   - 1-sample chunks shrink LDS to 32KB/block (posBuf 4dw + stash 12dw per
//     ray per wave) at zero extra per-sample cost (tile = 16 rays x 1 sample)
//   - grid 1024 blocks -> 4 blocks/CU x 8 waves = 32 waves/CU (2x residency)
//   - __launch_bounds__(512,8): 8 waves/SIMD needs <=64 VGPR (have 52)
// Partial composite states merged by R15-proven combine kernel.

typedef float  f32x4  __attribute__((ext_vector_type(4)));
typedef short  bf16x8 __attribute__((ext_vector_type(8)));
typedef unsigned int u32;

__device__ __forceinline__ float fast_rcp(float x){ return __builtin_amdgcn_rcpf(x); }
__device__ __forceinline__ float softplus_f(float x){
    float e = __expf(-fabsf(x));
    return fmaxf(x,0.f) + __logf(1.f+e);
}
__device__ __forceinline__ float sigmoid_f(float x){ return fast_rcp(1.f+__expf(-x)); }

// truncation pack (1 op): (bf16(hi)<<16)|bf16(lo), RTZ
__device__ __forceinline__ u32 pktr(float lo, float hi){
    return __builtin_amdgcn_perm(__float_as_uint(hi), __float_as_uint(lo), 0x07060302u);
}
// exact RNE pack (cold paths)
__device__ __forceinline__ u32 bfr_hi(float f){
    u32 u = __float_as_uint(f);
    return (u + 0x7FFFu + ((u>>16)&1u)) & 0xFFFF0000u;
}
__device__ __forceinline__ u32 pkbf(float lo, float hi){
    return (bfr_hi(lo)>>16) | bfr_hi(hi);
}

// ---- prep: identical to R12-R17 (proven) ----
__global__ __launch_bounds__(256)
void nerf_prep_kernel(const float* __restrict__ W1, const float* __restrict__ b1,
                      const float* __restrict__ Wsig, const float* __restrict__ Wsig_d,
                      const float* __restrict__ Wc1, const float* __restrict__ bc1,
                      const float* __restrict__ Wc2, const float* __restrict__ Wc2_d,
                      u32* __restrict__ ws)
{
    const int q0 = threadIdx.x;
#pragma unroll
    for (int k = 0; k < 6; ++k) {
        const int q = q0 + k*256;
        u32 val = 0u;
        if (q < 1024) {
            const int ut = q>>8, rem = q&255, lane = rem>>2, dw = rem&3;
            const int g = lane>>4, m = lane&15;
            if (g == 0) {
                float w[8];
                if (ut < 2) { const int u = ut*16 + m;
                    w[0]=W1[u];  w[1]=W1[32+u];  w[2]=W1[64+u];  w[3]=b1[u];
                    w[4]=0.f;    w[5]=0.f;       w[6]=0.f;       w[7]=0.f;
                } else {        const int u = (ut-2)*16 + m;
                    w[0]=Wc1[u]; w[1]=Wc1[32+u]; w[2]=Wc1[64+u]; w[3]=bc1[u];
                    w[4]=Wc1[96+u]; w[5]=Wc1[128+u]; w[6]=Wc1[160+u]; w[7]=0.f;
                }
                val = pkbf(w[2*dw], w[2*dw+1]);
            }
        } else {
            const int q2 = q-1024, ch = q2>>8, rem = q2&255, lane = rem>>2, dw = rem&3;
            const int g = lane>>4, o = lane&15;
            float w[2];
#pragma unroll
            for (int e = 0; e < 2; ++e) {
                const int kk = 2*dw + e;
                const int h = kk>>2, rr = kk&3;
                const int u_local = h*16 + g*4 + rr;
                float v = 0.f;
                if (ch == 0) {
                    if (o == 0) v = Wsig[u_local];
                    else if (o == 1) v = Wsig_d[u_local];
                } else {
                    if (o >= 2 && o <= 4) v = Wc2[u_local*3 + (o-2)];
                    else if (o >= 5 && o <= 7) v = Wc2_d[u_local*3 + (o-5)];
                }
                w[e] = v;
            }
            val = pkbf(w[0], w[1]);
        }
        ws[q] = val;
    }
}

#define PSTR 4     // posBuf ray stride (dw): 1 sample = 1 uint4
#define SSTR 12    // stash ray stride (dw): 8 outputs + 4 pad
#define WSTR 1024  // per-wave LDS dwords: 64*PSTR + 64*SSTR = 256 + 768
#define CSTR 100   // combine ray stride (dw)
#define PART_OFF 2048   // dword offset of partial states in d_ws
#define LOG2E 1.44269504088896340736f

// ---- render: block = 8 waves = 64 rays x halfT samples; 2 blocks per ray ----
__global__ __launch_bounds__(512, 8)
void nerf_render_kernel(const float* __restrict__ rays_o,
                        const float* __restrict__ rays_d,
                        const u32*  __restrict__ wsm,
                        const int*  __restrict__ num_steps,
                        float* __restrict__ partials,
                        int N)
{
    __shared__ u32 smem[8 * WSTR];   // 32 768 B

    const int tid  = threadIdx.x;
    const int seg  = tid>>6, lane = tid&63;    // seg 0..7
    const int half = blockIdx.x & 1;
    const int ray  = (blockIdx.x >> 1)*64 + lane;
    const int rayc = (ray < N) ? ray : (N-1);
    const int T = num_steps[0];
    const int g = lane>>4, c = lane&15;

    u32*   posW   = smem + seg*WSTR;
    float* stashW = (float*)(smem + seg*WSTR + 64*PSTR);
    float* comb   = (float*)smem;    // aliased; used only after barrier

    // weight fragments (proven layout), pinned
    const uint4* wsv = (const uint4*)wsm;
    uint4 a1u0 = wsv[0*64 + lane];
    uint4 a1u1 = wsv[1*64 + lane];
    uint4 a1u2 = wsv[2*64 + lane];
    uint4 a1u3 = wsv[3*64 + lane];
    uint4 a2u0 = wsv[256 + 0*64 + lane];
    uint4 a2u1 = wsv[256 + 1*64 + lane];
    asm volatile("" : "+v"(a1u0.x), "+v"(a1u0.y), "+v"(a1u0.z), "+v"(a1u0.w),
                      "+v"(a1u1.x), "+v"(a1u1.y), "+v"(a1u1.z), "+v"(a1u1.w),
                      "+v"(a1u2.x), "+v"(a1u2.y), "+v"(a1u2.z), "+v"(a1u2.w));
    asm volatile("" : "+v"(a1u3.x), "+v"(a1u3.y), "+v"(a1u3.z), "+v"(a1u3.w),
                      "+v"(a2u0.x), "+v"(a2u0.y), "+v"(a2u0.z), "+v"(a2u0.w),
                      "+v"(a2u1.x), "+v"(a2u1.y), "+v"(a2u1.z), "+v"(a2u1.w));

    // own-ray setup
    const float ox = rays_o[rayc*3+0], oy = rays_o[rayc*3+1], oz = rays_o[rayc*3+2];
    const float rdx = rays_d[rayc*3+0], rdy = rays_d[rayc*3+1], rdz = rays_d[rayc*3+2];
    const float rn = rsqrtf(rdx*rdx + rdy*rdy + rdz*rdz);
    const float dx = rdx*rn, dy = rdy*rn, dz = rdz*rn;

    const float ix = 1.0f/dx, iy = 1.0f/dy, iz = 1.0f/dz;
    const float t1x = (-1.f-ox)*ix, t2x = (1.f-ox)*ix;
    const float t1y = (-1.f-oy)*iy, t2y = (1.f-oy)*iy;
    const float t1z = (-1.f-oz)*iz, t2z = (1.f-oz)*iz;
    float nearv = fmaxf(fmaxf(fminf(t1x,t2x), fminf(t1y,t2y)), fminf(t1z,t2z));
    float farv  = fminf(fminf(fmaxf(t1x,t2x), fmaxf(t1y,t2y)), fmaxf(t1z,t2z));
    nearv = fmaxf(nearv, 0.2f);
    farv  = fmaxf(farv, nearv + 1e-6f);

    const float span    = farv - nearv;
    const float stepz   = (T > 1) ? span/(float)(T-1) : 0.f;
    const float inv_tm1 = (T > 1) ? 1.f/(float)(T-1) : 0.f;
    const float last_dt = span/(float)T;
    const float nStep2  = -stepz  * LOG2E;
    const float nLast2  = -last_dt * LOG2E;

    const u32 dirw0 = pkbf(dx, dy);
    const u32 dirw1 = pkbf(dz, 0.f);

    // this block covers samples [half*halfT, (half+1)*halfT); wave = Sper of them
    const int halfT = (T + 1) >> 1;
    const int Sper  = (halfT + 7) >> 3;
    const int hEnd  = ((half + 1)*halfT < T) ? (half + 1)*halfT : T;
    const int segStart = half*halfT + seg*Sper;
    int segEnd = segStart + Sper;
    segEnd = (segEnd < hEnd) ? segEnd : hEnd;
    const int nch = (segEnd > segStart) ? (segEnd - segStart) : 0;

    // per-lane constant LDS offsets (dwords)
    const int posOff = 4*c;                 // within tile: ray c -> c*PSTR
    const int stOff  = c*SSTR + g*4;        // within tile: ray c, rows g*4..+3

    float iA0=0.f,iA1=0.f,iA2=0.f,dAc=0.f,wsA=0.f,TAx=1.f;
    float iD0=0.f,iD1=0.f,iD2=0.f,dDc=0.f,wsD=0.f,TDx=1.f;
    const f32x4 z4 = {0.f,0.f,0.f,0.f};

    for (int cs = 0; cs < nch; ++cs) {
        const int tg = segStart + cs;

        // ---- phase A: own-ray B1 column for this sample -> posBuf ----
        {
            const float zv = fmaf(stepz, (float)tg, nearv);
            const float X = fminf(fmaxf(fmaf(dx, zv, ox), -1.f), 1.f);
            const float Y = fminf(fmaxf(fmaf(dy, zv, oy), -1.f), 1.f);
            const float Z = fminf(fmaxf(fmaf(dz, zv, oz), -1.f), 1.f);
            uint4 v;
            v.x = pktr(X, Y);
            v.y = pktr(Z, 1.0f);
            v.z = dirw0;
            v.w = dirw1;
            *(uint4*)&posW[lane*PSTR] = v;
        }

        // ---- phase B: 4 MFMA tiles (tile TAU = rays 16*TAU..16*TAU+15) ----
        __builtin_amdgcn_s_setprio(1);
#define TILEB(TAU)                                                                \
        {                                                                         \
            const uint4 b1u = *(const uint4*)&posW[(TAU)*(16*PSTR) + posOff];     \
            const bf16x8 b1f = __builtin_bit_cast(bf16x8, b1u);                   \
            f32x4 acc10 = __builtin_amdgcn_mfma_f32_16x16x32_bf16(                \
                __builtin_bit_cast(bf16x8, a1u0), b1f, z4, 0,0,0);                \
            f32x4 acc11 = __builtin_amdgcn_mfma_f32_16x16x32_bf16(                \
                __builtin_bit_cast(bf16x8, a1u1), b1f, z4, 0,0,0);                \
            f32x4 acc12 = __builtin_amdgcn_mfma_f32_16x16x32_bf16(                \
                __builtin_bit_cast(bf16x8, a1u2), b1f, z4, 0,0,0);                \
            f32x4 acc13 = __builtin_amdgcn_mfma_f32_16x16x32_bf16(                \
                __builtin_bit_cast(bf16x8, a1u3), b1f, z4, 0,0,0);                \
            const f32x4 r0 = __builtin_elementwise_max(acc10, z4);                \
            const f32x4 r1 = __builtin_elementwise_max(acc11, z4);                \
            const f32x4 r2 = __builtin_elementwise_max(acc12, z4);                \
            const f32x4 r3 = __builtin_elementwise_max(acc13, z4);                \
            uint4 b2a, b2b;                                                       \
            b2a.x = pktr(r0.x, r0.y);  b2a.y = pktr(r0.z, r0.w);                  \
            b2a.z = pktr(r1.x, r1.y);  b2a.w = pktr(r1.z, r1.w);                  \
            b2b.x = pktr(r2.x, r2.y);  b2b.y = pktr(r2.z, r2.w);                  \
            b2b.z = pktr(r3.x, r3.y);  b2b.w = pktr(r3.z, r3.w);                  \
            f32x4 acc2 = __builtin_amdgcn_mfma_f32_16x16x32_bf16(                 \
                __builtin_bit_cast(bf16x8, a2u0), __builtin_bit_cast(bf16x8, b2a),\
                z4, 0, 0, 0);                                                     \
            acc2 = __builtin_amdgcn_mfma_f32_16x16x32_bf16(                       \
                __builtin_bit_cast(bf16x8, a2u1), __builtin_bit_cast(bf16x8, b2b),\
                acc2, 0, 0, 0);                                                   \
            if (g < 2) {                                                          \
                *(f32x4*)&stashW[(TAU)*(16*SSTR) + stOff] = acc2;                 \
            }                                                                     \
        }
        TILEB(0) TILEB(1) TILEB(2) TILEB(3)
#undef TILEB
        __builtin_amdgcn_s_setprio(0);

        // ---- phase C: composite own ray's sample ----
        {
            const f32x4 oA = *(const f32x4*)&stashW[lane*SSTR];
            const f32x4 oB = *(const f32x4*)&stashW[lane*SSTR + 4];
            const float dneg2 = (tg < T-1) ? nStep2 : nLast2;
            const float z01   = (float)tg * inv_tm1;

            const float sigA = softplus_f(oA.x);
            const float qA = exp2f(dneg2*sigA);
            const float wA = TAx - TAx*qA; TAx *= qA;
            iA0 = fmaf(wA, sigmoid_f(oA.z), iA0);
            iA1 = fmaf(wA, sigmoid_f(oA.w), iA1);
            iA2 = fmaf(wA, sigmoid_f(oB.x), iA2);
            dAc = fmaf(wA, z01, dAc); wsA += wA;

            const float sigD = softplus_f(oA.y);
            const float qD = exp2f(dneg2*sigD);
            const float wD = TDx - TDx*qD; TDx *= qD;
            iD0 = fmaf(wD, sigmoid_f(oB.y), iD0);
            iD1 = fmaf(wD, sigmoid_f(oB.z), iD1);
            iD2 = fmaf(wD, sigmoid_f(oB.w), iD2);
            dDc = fmaf(wD, z01, dDc); wsD += wD;
        }
    }

    // ---- combine the 8 waves' segment states (comb aliases smem) ----
    __syncthreads();
    *(f32x4*)&comb[lane*CSTR + seg*12 + 0] = (f32x4){iA0, iA1, iA2, dAc};
    *(f32x4*)&comb[lane*CSTR + seg*12 + 4] = (f32x4){wsA, TAx, iD0, iD1};
    *(f32x4*)&comb[lane*CSTR + seg*12 + 8] = (f32x4){iD2, dDc, wsD, TDx};
    __syncthreads();

    if (seg == 0 && ray < N) {
        float tA = TAx, tD = TDx;
#pragma unroll
        for (int s = 1; s < 8; ++s) {
            const f32x4 v0 = *(const f32x4*)&comb[lane*CSTR + s*12 + 0];
            const f32x4 v1 = *(const f32x4*)&comb[lane*CSTR + s*12 + 4];
            const f32x4 v2 = *(const f32x4*)&comb[lane*CSTR + s*12 + 8];
            iA0 = fmaf(tA, v0.x, iA0);
            iA1 = fmaf(tA, v0.y, iA1);
            iA2 = fmaf(tA, v0.z, iA2);
            dAc = fmaf(tA, v0.w, dAc);
            wsA = fmaf(tA, v1.x, wsA);
            tA *= v1.y;
            iD0 = fmaf(tD, v1.z, iD0);
            iD1 = fmaf(tD, v1.w, iD1);
            iD2 = fmaf(tD, v2.x, iD2);
            dDc = fmaf(tD, v2.y, dDc);
            wsD = fmaf(tD, v2.z, wsD);
            tD *= v2.w;
        }
        float* pw = partials + (size_t)(half*N + ray)*12;
        *(f32x4*)&pw[0] = (f32x4){iA0, iA1, iA2, dAc};
        *(f32x4*)&pw[4] = (f32x4){wsA, tA, iD0, iD1};
        *(f32x4*)&pw[8] = (f32x4){iD2, dDc, wsD, tD};
    }
}

// ---- combine: one lane per ray, merge the two halves (R15-proven) ----
__global__ __launch_bounds__(256)
void nerf_combine_kernel(const float* __restrict__ partials,
                         float* __restrict__ out, int N)
{
    const int ray = blockIdx.x*256 + threadIdx.x;
    if (ray >= N) return;
    const float* p0 = partials + (size_t)ray*12;
    const float* p1 = partials + (size_t)(N + ray)*12;
    const f32x4 a0 = *(const f32x4*)&p0[0];
    const f32x4 a1 = *(const f32x4*)&p0[4];
    const f32x4 a2 = *(const f32x4*)&p0[8];
    const f32x4 b0 = *(const f32x4*)&p1[0];
    const f32x4 b1 = *(const f32x4*)&p1[4];
    const f32x4 b2 = *(const f32x4*)&p1[8];

    const float TA0 = a1.y, TD0 = a2.w;
    const float iA0 = a0.x + TA0*b0.x;
    const float iA1 = a0.y + TA0*b0.y;
    const float iA2 = a0.z + TA0*b0.z;
    const float dAc = a0.w + TA0*b0.w;
    const float wsA = a1.x + TA0*b1.x;
    const float iD0 = a1.z + TD0*b1.z;
    const float iD1 = a1.w + TD0*b1.w;
    const float iD2 = a2.x + TD0*b2.x;
    const float dDc = a2.y + TD0*b2.y;
    const float wsD = a2.z + TD0*b2.z;

    const float bgA = 1.f - wsA;
    const float bgD = 1.f - wsD;
    float* o = out + (size_t)ray * 9;
    o[0] = iA0 + bgA;
    o[1] = iA1 + bgA;
    o[2] = iA2 + bgA;
    o[3] = dAc;
    o[4] = wsA;
    o[5] = iD0 + bgD;
    o[6] = iD1 + bgD;
    o[7] = iD2 + bgD;
    o[8] = dDc;
}

extern "C" void kernel_launch(void* const* d_in, const int* in_sizes, int n_in,
                              void* d_out, int out_size, void* d_ws, size_t ws_size,
                              hipStream_t stream) {
    const float* rays_o = (const float*)d_in[0];
    const float* rays_d = (const float*)d_in[1];
    const float* W1     = (const float*)d_in[2];
    const float* b1     = (const float*)d_in[3];
    const float* Wsig   = (const float*)d_in[4];
    const float* Wsig_d = (const float*)d_in[5];
    const float* Wc1    = (const float*)d_in[6];
    const float* bc1    = (const float*)d_in[7];
    const float* Wc2    = (const float*)d_in[8];
    const float* Wc2_d  = (const float*)d_in[9];
    const int* num_steps = (const int*)d_in[10];

    const int N = in_sizes[0] / 3;
    float* out = (float*)d_out;
    u32*   ws  = (u32*)d_ws;
    float* partials = (float*)((u32*)d_ws + PART_OFF);  // 2*N*12 floats

    hipLaunchKernelGGL(nerf_prep_kernel, dim3(1), dim3(256), 0, stream,
                       W1, b1, Wsig, Wsig_d, Wc1, bc1, Wc2, Wc2_d, ws);

    const int rblocks = ((N + 63) / 64) * 2;   // 64 rays x half-T per block
    hipLaunchKernelGGL(nerf_render_kernel, dim3(rblocks), dim3(512), 0, stream,
                       rays_o, rays_d, ws, num_steps, partials, N);

    const int cblocks = (N + 255) / 256;
    hipLaunchKernelGGL(nerf_combine_kernel, dim3(cblocks), dim3(256), 0, stream,
                       partials, out, N);
}

// Round 19
// 53.232 us; speedup vs baseline: 1.2003x; 1.2003x over previous
//
#include <hip/hip_runtime.h>
#include <hip/hip_bf16.h>

// NeRF surrogate renderer, MI355X — round 19: residency without spills.
// R18: launch_bounds(512,8) doubled occupancy (33->65%) but the 64-VGPR cap
// spilled (FETCH 465KB->17.6MB) -> net regression. This round: same structure
// (T-split x2, 1-sample chunks, 32KB LDS) with launch_bounds(512,6):
// <=84 VGPR budget (kernel needs ~60) -> no spills, 3 blocks/CU = 24 waves/CU
// (1.5x R17 residency). Isolates the residency lever from the spill confound.

typedef float  f32x4  __attribute__((ext_vector_type(4)));
typedef short  bf16x8 __attribute__((ext_vector_type(8)));
typedef unsigned int u32;

__device__ __forceinline__ float fast_rcp(float x){ return __builtin_amdgcn_rcpf(x); }
__device__ __forceinline__ float softplus_f(float x){
    float e = __expf(-fabsf(x));
    return fmaxf(x,0.f) + __logf(1.f+e);
}
__device__ __forceinline__ float sigmoid_f(float x){ return fast_rcp(1.f+__expf(-x)); }

// truncation pack (1 op): (bf16(hi)<<16)|bf16(lo), RTZ
__device__ __forceinline__ u32 pktr(float lo, float hi){
    return __builtin_amdgcn_perm(__float_as_uint(hi), __float_as_uint(lo), 0x07060302u);
}
// exact RNE pack (cold paths)
__device__ __forceinline__ u32 bfr_hi(float f){
    u32 u = __float_as_uint(f);
    return (u + 0x7FFFu + ((u>>16)&1u)) & 0xFFFF0000u;
}
__device__ __forceinline__ u32 pkbf(float lo, float hi){
    return (bfr_hi(lo)>>16) | bfr_hi(hi);
}

// ---- prep: identical to R12-R18 (proven) ----
__global__ __launch_bounds__(256)
void nerf_prep_kernel(const float* __restrict__ W1, const float* __restrict__ b1,
                      const float* __restrict__ Wsig, const float* __restrict__ Wsig_d,
                      const float* __restrict__ Wc1, const float* __restrict__ bc1,
                      const float* __restrict__ Wc2, const float* __restrict__ Wc2_d,
                      u32* __restrict__ ws)
{
    const int q0 = threadIdx.x;
#pragma unroll
    for (int k = 0; k < 6; ++k) {
        const int q = q0 + k*256;
        u32 val = 0u;
        if (q < 1024) {
            const int ut = q>>8, rem = q&255, lane = rem>>2, dw = rem&3;
            const int g = lane>>4, m = lane&15;
            if (g == 0) {
                float w[8];
                if (ut < 2) { const int u = ut*16 + m;
                    w[0]=W1[u];  w[1]=W1[32+u];  w[2]=W1[64+u];  w[3]=b1[u];
                    w[4]=0.f;    w[5]=0.f;       w[6]=0.f;       w[7]=0.f;
                } else {        const int u = (ut-2)*16 + m;
                    w[0]=Wc1[u]; w[1]=Wc1[32+u]; w[2]=Wc1[64+u]; w[3]=bc1[u];
                    w[4]=Wc1[96+u]; w[5]=Wc1[128+u]; w[6]=Wc1[160+u]; w[7]=0.f;
                }
                val = pkbf(w[2*dw], w[2*dw+1]);
            }
        } else {
            const int q2 = q-1024, ch = q2>>8, rem = q2&255, lane = rem>>2, dw = rem&3;
            const int g = lane>>4, o = lane&15;
            float w[2];
#pragma unroll
            for (int e = 0; e < 2; ++e) {
                const int kk = 2*dw + e;
                const int h = kk>>2, rr = kk&3;
                const int u_local = h*16 + g*4 + rr;
                float v = 0.f;
                if (ch == 0) {
                    if (o == 0) v = Wsig[u_local];
                    else if (o == 1) v = Wsig_d[u_local];
                } else {
                    if (o >= 2 && o <= 4) v = Wc2[u_local*3 + (o-2)];
                    else if (o >= 5 && o <= 7) v = Wc2_d[u_local*3 + (o-5)];
                }
                w[e] = v;
            }
            val = pkbf(w[0], w[1]);
        }
        ws[q] = val;
    }
}

#define PSTR 4     // posBuf ray stride (dw): 1 sample = 1 uint4
#define SSTR 12    // stash ray stride (dw): 8 outputs + 4 pad
#define WSTR 1024  // per-wave LDS dwords: 64*PSTR + 64*SSTR = 256 + 768
#define CSTR 100   // combine ray stride (dw)
#define PART_OFF 2048   // dword offset of partial states in d_ws
#define LOG2E 1.44269504088896340736f

// ---- render: block = 8 waves = 64 rays x halfT samples; 2 blocks per ray ----
__global__ __launch_bounds__(512, 6)
void nerf_render_kernel(const float* __restrict__ rays_o,
                        const float* __restrict__ rays_d,
                        const u32*  __restrict__ wsm,
                        const int*  __restrict__ num_steps,
                        float* __restrict__ partials,
                        int N)
{
    __shared__ u32 smem[8 * WSTR];   // 32 768 B

    const int tid  = threadIdx.x;
    const int seg  = tid>>6, lane = tid&63;    // seg 0..7
    const int half = blockIdx.x & 1;
    const int ray  = (blockIdx.x >> 1)*64 + lane;
    const int rayc = (ray < N) ? ray : (N-1);
    const int T = num_steps[0];
    const int g = lane>>4, c = lane&15;

    u32*   posW   = smem + seg*WSTR;
    float* stashW = (float*)(smem + seg*WSTR + 64*PSTR);
    float* comb   = (float*)smem;    // aliased; used only after barrier

    // weight fragments (proven layout), pinned
    const uint4* wsv = (const uint4*)wsm;
    uint4 a1u0 = wsv[0*64 + lane];
    uint4 a1u1 = wsv[1*64 + lane];
    uint4 a1u2 = wsv[2*64 + lane];
    uint4 a1u3 = wsv[3*64 + lane];
    uint4 a2u0 = wsv[256 + 0*64 + lane];
    uint4 a2u1 = wsv[256 + 1*64 + lane];
    asm volatile("" : "+v"(a1u0.x), "+v"(a1u0.y), "+v"(a1u0.z), "+v"(a1u0.w),
                      "+v"(a1u1.x), "+v"(a1u1.y), "+v"(a1u1.z), "+v"(a1u1.w),
                      "+v"(a1u2.x), "+v"(a1u2.y), "+v"(a1u2.z), "+v"(a1u2.w));
    asm volatile("" : "+v"(a1u3.x), "+v"(a1u3.y), "+v"(a1u3.z), "+v"(a1u3.w),
                      "+v"(a2u0.x), "+v"(a2u0.y), "+v"(a2u0.z), "+v"(a2u0.w),
                      "+v"(a2u1.x), "+v"(a2u1.y), "+v"(a2u1.z), "+v"(a2u1.w));

    // own-ray setup
    const float ox = rays_o[rayc*3+0], oy = rays_o[rayc*3+1], oz = rays_o[rayc*3+2];
    const float rdx = rays_d[rayc*3+0], rdy = rays_d[rayc*3+1], rdz = rays_d[rayc*3+2];
    const float rn = rsqrtf(rdx*rdx + rdy*rdy + rdz*rdz);
    const float dx = rdx*rn, dy = rdy*rn, dz = rdz*rn;

    const float ix = 1.0f/dx, iy = 1.0f/dy, iz = 1.0f/dz;
    const float t1x = (-1.f-ox)*ix, t2x = (1.f-ox)*ix;
    const float t1y = (-1.f-oy)*iy, t2y = (1.f-oy)*iy;
    const float t1z = (-1.f-oz)*iz, t2z = (1.f-oz)*iz;
    float nearv = fmaxf(fmaxf(fminf(t1x,t2x), fminf(t1y,t2y)), fminf(t1z,t2z));
    float farv  = fminf(fminf(fmaxf(t1x,t2x), fmaxf(t1y,t2y)), fmaxf(t1z,t2z));
    nearv = fmaxf(nearv, 0.2f);
    farv  = fmaxf(farv, nearv + 1e-6f);

    const float span    = farv - nearv;
    const float stepz   = (T > 1) ? span/(float)(T-1) : 0.f;
    const float inv_tm1 = (T > 1) ? 1.f/(float)(T-1) : 0.f;
    const float last_dt = span/(float)T;
    const float nStep2  = -stepz  * LOG2E;
    const float nLast2  = -last_dt * LOG2E;

    const u32 dirw0 = pkbf(dx, dy);
    const u32 dirw1 = pkbf(dz, 0.f);

    // this block covers samples [half*halfT, (half+1)*halfT); wave = Sper of them
    const int halfT = (T + 1) >> 1;
    const int Sper  = (halfT + 7) >> 3;
    const int hEnd  = ((half + 1)*halfT < T) ? (half + 1)*halfT : T;
    const int segStart = half*halfT + seg*Sper;
    int segEnd = segStart + Sper;
    segEnd = (segEnd < hEnd) ? segEnd : hEnd;
    const int nch = (segEnd > segStart) ? (segEnd - segStart) : 0;

    // per-lane constant LDS offsets (dwords)
    const int posOff = 4*c;                 // within tile: ray c -> c*PSTR
    const int stOff  = c*SSTR + g*4;        // within tile: ray c, rows g*4..+3

    float iA0=0.f,iA1=0.f,iA2=0.f,dAc=0.f,wsA=0.f,TAx=1.f;
    float iD0=0.f,iD1=0.f,iD2=0.f,dDc=0.f,wsD=0.f,TDx=1.f;
    const f32x4 z4 = {0.f,0.f,0.f,0.f};

    for (int cs = 0; cs < nch; ++cs) {
        const int tg = segStart + cs;

        // ---- phase A: own-ray B1 column for this sample -> posBuf ----
        {
            const float zv = fmaf(stepz, (float)tg, nearv);
            const float X = fminf(fmaxf(fmaf(dx, zv, ox), -1.f), 1.f);
            const float Y = fminf(fmaxf(fmaf(dy, zv, oy), -1.f), 1.f);
            const float Z = fminf(fmaxf(fmaf(dz, zv, oz), -1.f), 1.f);
            uint4 v;
            v.x = pktr(X, Y);
            v.y = pktr(Z, 1.0f);
            v.z = dirw0;
            v.w = dirw1;
            *(uint4*)&posW[lane*PSTR] = v;
        }

        // ---- phase B: 4 MFMA tiles (tile TAU = rays 16*TAU..16*TAU+15) ----
        __builtin_amdgcn_s_setprio(1);
#define TILEB(TAU)                                                                \
        {                                                                         \
            const uint4 b1u = *(const uint4*)&posW[(TAU)*(16*PSTR) + posOff];     \
            const bf16x8 b1f = __builtin_bit_cast(bf16x8, b1u);                   \
            f32x4 acc10 = __builtin_amdgcn_mfma_f32_16x16x32_bf16(                \
                __builtin_bit_cast(bf16x8, a1u0), b1f, z4, 0,0,0);                \
            f32x4 acc11 = __builtin_amdgcn_mfma_f32_16x16x32_bf16(                \
                __builtin_bit_cast(bf16x8, a1u1), b1f, z4, 0,0,0);                \
            f32x4 acc12 = __builtin_amdgcn_mfma_f32_16x16x32_bf16(                \
                __builtin_bit_cast(bf16x8, a1u2), b1f, z4, 0,0,0);                \
            f32x4 acc13 = __builtin_amdgcn_mfma_f32_16x16x32_bf16(                \
                __builtin_bit_cast(bf16x8, a1u3), b1f, z4, 0,0,0);                \
            const f32x4 r0 = __builtin_elementwise_max(acc10, z4);                \
            const f32x4 r1 = __builtin_elementwise_max(acc11, z4);                \
            const f32x4 r2 = __builtin_elementwise_max(acc12, z4);                \
            const f32x4 r3 = __builtin_elementwise_max(acc13, z4);                \
            uint4 b2a, b2b;                                                       \
            b2a.x = pktr(r0.x, r0.y);  b2a.y = pktr(r0.z, r0.w);                  \
            b2a.z = pktr(r1.x, r1.y);  b2a.w = pktr(r1.z, r1.w);                  \
            b2b.x = pktr(r2.x, r2.y);  b2b.y = pktr(r2.z, r2.w);                  \
            b2b.z = pktr(r3.x, r3.y);  b2b.w = pktr(r3.z, r3.w);                  \
            f32x4 acc2 = __builtin_amdgcn_mfma_f32_16x16x32_bf16(                 \
                __builtin_bit_cast(bf16x8, a2u0), __builtin_bit_cast(bf16x8, b2a),\
                z4, 0, 0, 0);                                                     \
            acc2 = __builtin_amdgcn_mfma_f32_16x16x32_bf16(                       \
                __builtin_bit_cast(bf16x8, a2u1), __builtin_bit_cast(bf16x8, b2b),\
                acc2, 0, 0, 0);                                                   \
            if (g < 2) {                                                          \
                *(f32x4*)&stashW[(TAU)*(16*SSTR) + stOff] = acc2;                 \
            }                                                                     \
        }
        TILEB(0) TILEB(1) TILEB(2) TILEB(3)
#undef TILEB
        __builtin_amdgcn_s_setprio(0);

        // ---- phase C: composite own ray's sample ----
        {
            const f32x4 oA = *(const f32x4*)&stashW[lane*SSTR];
            const f32x4 oB = *(const f32x4*)&stashW[lane*SSTR + 4];
            const float dneg2 = (tg < T-1) ? nStep2 : nLast2;
            const float z01   = (float)tg * inv_tm1;

            const float sigA = softplus_f(oA.x);
            const float qA = exp2f(dneg2*sigA);
            const float wA = TAx - TAx*qA; TAx *= qA;
            iA0 = fmaf(wA, sigmoid_f(oA.z), iA0);
            iA1 = fmaf(wA, sigmoid_f(oA.w), iA1);
            iA2 = fmaf(wA, sigmoid_f(oB.x), iA2);
            dAc = fmaf(wA, z01, dAc); wsA += wA;

            const float sigD = softplus_f(oA.y);
            const float qD = exp2f(dneg2*sigD);
            const float wD = TDx - TDx*qD; TDx *= qD;
            iD0 = fmaf(wD, sigmoid_f(oB.y), iD0);
            iD1 = fmaf(wD, sigmoid_f(oB.z), iD1);
            iD2 = fmaf(wD, sigmoid_f(oB.w), iD2);
            dDc = fmaf(wD, z01, dDc); wsD += wD;
        }
    }

    // ---- combine the 8 waves' segment states (comb aliases smem) ----
    __syncthreads();
    *(f32x4*)&comb[lane*CSTR + seg*12 + 0] = (f32x4){iA0, iA1, iA2, dAc};
    *(f32x4*)&comb[lane*CSTR + seg*12 + 4] = (f32x4){wsA, TAx, iD0, iD1};
    *(f32x4*)&comb[lane*CSTR + seg*12 + 8] = (f32x4){iD2, dDc, wsD, TDx};
    __syncthreads();

    if (seg == 0 && ray < N) {
        float tA = TAx, tD = TDx;
#pragma unroll
        for (int s = 1; s < 8; ++s) {
            const f32x4 v0 = *(const f32x4*)&comb[lane*CSTR + s*12 + 0];
            const f32x4 v1 = *(const f32x4*)&comb[lane*CSTR + s*12 + 4];
            const f32x4 v2 = *(const f32x4*)&comb[lane*CSTR + s*12 + 8];
            iA0 = fmaf(tA, v0.x, iA0);
            iA1 = fmaf(tA, v0.y, iA1);
            iA2 = fmaf(tA, v0.z, iA2);
            dAc = fmaf(tA, v0.w, dAc);
            wsA = fmaf(tA, v1.x, wsA);
            tA *= v1.y;
            iD0 = fmaf(tD, v1.z, iD0);
            iD1 = fmaf(tD, v1.w, iD1);
            iD2 = fmaf(tD, v2.x, iD2);
            dDc = fmaf(tD, v2.y, dDc);
            wsD = fmaf(tD, v2.z, wsD);
            tD *= v2.w;
        }
        float* pw = partials + (size_t)(half*N + ray)*12;
        *(f32x4*)&pw[0] = (f32x4){iA0, iA1, iA2, dAc};
        *(f32x4*)&pw[4] = (f32x4){wsA, tA, iD0, iD1};
        *(f32x4*)&pw[8] = (f32x4){iD2, dDc, wsD, tD};
    }
}

// ---- combine: one lane per ray, merge the two halves (R15-proven) ----
__global__ __launch_bounds__(256)
void nerf_combine_kernel(const float* __restrict__ partials,
                         float* __restrict__ out, int N)
{
    const int ray = blockIdx.x*256 + threadIdx.x;
    if (ray >= N) return;
    const float* p0 = partials + (size_t)ray*12;
    const float* p1 = partials + (size_t)(N + ray)*12;
    const f32x4 a0 = *(const f32x4*)&p0[0];
    const f32x4 a1 = *(const f32x4*)&p0[4];
    const f32x4 a2 = *(const f32x4*)&p0[8];
    const f32x4 b0 = *(const f32x4*)&p1[0];
    const f32x4 b1 = *(const f32x4*)&p1[4];
    const f32x4 b2 = *(const f32x4*)&p1[8];

    const float TA0 = a1.y, TD0 = a2.w;
    const float iA0 = a0.x + TA0*b0.x;
    const float iA1 = a0.y + TA0*b0.y;
    const float iA2 = a0.z + TA0*b0.z;
    const float dAc = a0.w + TA0*b0.w;
    const float wsA = a1.x + TA0*b1.x;
    const float iD0 = a1.z + TD0*b1.z;
    const float iD1 = a1.w + TD0*b1.w;
    const float iD2 = a2.x + TD0*b2.x;
    const float dDc = a2.y + TD0*b2.y;
    const float wsD = a2.z + TD0*b2.z;

    const float bgA = 1.f - wsA;
    const float bgD = 1.f - wsD;
    float* o = out + (size_t)ray * 9;
    o[0] = iA0 + bgA;
    o[1] = iA1 + bgA;
    o[2] = iA2 + bgA;
    o[3] = dAc;
    o[4] = wsA;
    o[5] = iD0 + bgD;
    o[6] = iD1 + bgD;
    o[7] = iD2 + bgD;
    o[8] = dDc;
}

extern "C" void kernel_launch(void* const* d_in, const int* in_sizes, int n_in,
                              void* d_out, int out_size, void* d_ws, size_t ws_size,
                              hipStream_t stream) {
    const float* rays_o = (const float*)d_in[0];
    const float* rays_d = (const float*)d_in[1];
    const float* W1     = (const float*)d_in[2];
    const float* b1     = (const float*)d_in[3];
    const float* Wsig   = (const float*)d_in[4];
    const float* Wsig_d = (const float*)d_in[5];
    const float* Wc1    = (const float*)d_in[6];
    const float* bc1    = (const float*)d_in[7];
    const float* Wc2    = (const float*)d_in[8];
    const float* Wc2_d  = (const float*)d_in[9];
    const int* num_steps = (const int*)d_in[10];

    const int N = in_sizes[0] / 3;
    float* out = (float*)d_out;
    u32*   ws  = (u32*)d_ws;
    float* partials = (float*)((u32*)d_ws + PART_OFF);  // 2*N*12 floats

    hipLaunchKernelGGL(nerf_prep_kernel, dim3(1), dim3(256), 0, stream,
                       W1, b1, Wsig, Wsig_d, Wc1, bc1, Wc2, Wc2_d, ws);

    const int rblocks = ((N + 63) / 64) * 2;   // 64 rays x half-T per block
    hipLaunchKernelGGL(nerf_render_kernel, dim3(rblocks), dim3(512), 0, stream,
                       rays_o, rays_d, ws, num_steps, partials, N);

    const int cblocks = (N + 255) / 256;
    hipLaunchKernelGGL(nerf_combine_kernel, dim3(cblocks), dim3(256), 0, stream,
                       partials, out, N);
}

// Round 20
// 52.181 us; speedup vs baseline: 1.2245x; 1.0202x over previous
//
#include <hip/hip_runtime.h>
#include <hip/hip_bf16.h>

// NeRF surrogate renderer, MI355X — round 20: consolidation.
// R19 evidence: residency NOT binding (occ 33->45% moved render only 0.5us);
// 1-sample chunks give ZERO bank conflicts (vs 1.57e6) and the fastest render;
// T-split's combine kernel costs ~5us for nothing. This round: single kernel,
// no T-split, 1-sample chunks, 32KB LDS, launch_bounds(512,6) (no spills),
// in-block 8-segment combine, direct out write. = R17 structure + R19 layout.

typedef float  f32x4  __attribute__((ext_vector_type(4)));
typedef short  bf16x8 __attribute__((ext_vector_type(8)));
typedef unsigned int u32;

__device__ __forceinline__ float fast_rcp(float x){ return __builtin_amdgcn_rcpf(x); }
__device__ __forceinline__ float softplus_f(float x){
    float e = __expf(-fabsf(x));
    return fmaxf(x,0.f) + __logf(1.f+e);
}
__device__ __forceinline__ float sigmoid_f(float x){ return fast_rcp(1.f+__expf(-x)); }

// truncation pack (1 op): (bf16(hi)<<16)|bf16(lo), RTZ
__device__ __forceinline__ u32 pktr(float lo, float hi){
    return __builtin_amdgcn_perm(__float_as_uint(hi), __float_as_uint(lo), 0x07060302u);
}
// exact RNE pack (cold paths)
__device__ __forceinline__ u32 bfr_hi(float f){
    u32 u = __float_as_uint(f);
    return (u + 0x7FFFu + ((u>>16)&1u)) & 0xFFFF0000u;
}
__device__ __forceinline__ u32 pkbf(float lo, float hi){
    return (bfr_hi(lo)>>16) | bfr_hi(hi);
}

// ---- prep: identical to R12-R19 (proven) ----
__global__ __launch_bounds__(256)
void nerf_prep_kernel(const float* __restrict__ W1, const float* __restrict__ b1,
                      const float* __restrict__ Wsig, const float* __restrict__ Wsig_d,
                      const float* __restrict__ Wc1, const float* __restrict__ bc1,
                      const float* __restrict__ Wc2, const float* __restrict__ Wc2_d,
                      u32* __restrict__ ws)
{
    const int q0 = threadIdx.x;
#pragma unroll
    for (int k = 0; k < 6; ++k) {
        const int q = q0 + k*256;
        u32 val = 0u;
        if (q < 1024) {
            const int ut = q>>8, rem = q&255, lane = rem>>2, dw = rem&3;
            const int g = lane>>4, m = lane&15;
            if (g == 0) {
                float w[8];
                if (ut < 2) { const int u = ut*16 + m;
                    w[0]=W1[u];  w[1]=W1[32+u];  w[2]=W1[64+u];  w[3]=b1[u];
                    w[4]=0.f;    w[5]=0.f;       w[6]=0.f;       w[7]=0.f;
                } else {        const int u = (ut-2)*16 + m;
                    w[0]=Wc1[u]; w[1]=Wc1[32+u]; w[2]=Wc1[64+u]; w[3]=bc1[u];
                    w[4]=Wc1[96+u]; w[5]=Wc1[128+u]; w[6]=Wc1[160+u]; w[7]=0.f;
                }
                val = pkbf(w[2*dw], w[2*dw+1]);
            }
        } else {
            const int q2 = q-1024, ch = q2>>8, rem = q2&255, lane = rem>>2, dw = rem&3;
            const int g = lane>>4, o = lane&15;
            float w[2];
#pragma unroll
            for (int e = 0; e < 2; ++e) {
                const int kk = 2*dw + e;
                const int h = kk>>2, rr = kk&3;
                const int u_local = h*16 + g*4 + rr;
                float v = 0.f;
                if (ch == 0) {
                    if (o == 0) v = Wsig[u_local];
                    else if (o == 1) v = Wsig_d[u_local];
                } else {
                    if (o >= 2 && o <= 4) v = Wc2[u_local*3 + (o-2)];
                    else if (o >= 5 && o <= 7) v = Wc2_d[u_local*3 + (o-5)];
                }
                w[e] = v;
            }
            val = pkbf(w[0], w[1]);
        }
        ws[q] = val;
    }
}

#define PSTR 4     // posBuf ray stride (dw): 1 sample = 1 uint4 (conflict-free)
#define SSTR 12    // stash ray stride (dw): 8 outputs + 4 pad (conflict-free)
#define WSTR 1024  // per-wave LDS dwords: 64*PSTR + 64*SSTR = 256 + 768
#define CSTR 100   // combine ray stride (dw)
#define LOG2E 1.44269504088896340736f

// ---- main: block = 8 waves = 64 rays x T samples (wave w = segment w) ----
__global__ __launch_bounds__(512, 6)
void nerf_render_kernel(const float* __restrict__ rays_o,
                        const float* __restrict__ rays_d,
                        const u32*  __restrict__ wsm,
                        const int*  __restrict__ num_steps,
                        float* __restrict__ out,
                        int N)
{
    __shared__ u32 smem[8 * WSTR];   // 32 768 B

    const int tid  = threadIdx.x;
    const int seg  = tid>>6, lane = tid&63;    // seg 0..7
    const int ray  = blockIdx.x*64 + lane;
    const int rayc = (ray < N) ? ray : (N-1);
    const int T = num_steps[0];
    const int g = lane>>4, c = lane&15;

    u32*   posW   = smem + seg*WSTR;
    float* stashW = (float*)(smem + seg*WSTR + 64*PSTR);
    float* comb   = (float*)smem;    // aliased; used only after barrier

    // weight fragments (proven layout), pinned
    const uint4* wsv = (const uint4*)wsm;
    uint4 a1u0 = wsv[0*64 + lane];
    uint4 a1u1 = wsv[1*64 + lane];
    uint4 a1u2 = wsv[2*64 + lane];
    uint4 a1u3 = wsv[3*64 + lane];
    uint4 a2u0 = wsv[256 + 0*64 + lane];
    uint4 a2u1 = wsv[256 + 1*64 + lane];
    asm volatile("" : "+v"(a1u0.x), "+v"(a1u0.y), "+v"(a1u0.z), "+v"(a1u0.w),
                      "+v"(a1u1.x), "+v"(a1u1.y), "+v"(a1u1.z), "+v"(a1u1.w),
                      "+v"(a1u2.x), "+v"(a1u2.y), "+v"(a1u2.z), "+v"(a1u2.w));
    asm volatile("" : "+v"(a1u3.x), "+v"(a1u3.y), "+v"(a1u3.z), "+v"(a1u3.w),
                      "+v"(a2u0.x), "+v"(a2u0.y), "+v"(a2u0.z), "+v"(a2u0.w),
                      "+v"(a2u1.x), "+v"(a2u1.y), "+v"(a2u1.z), "+v"(a2u1.w));

    // own-ray setup
    const float ox = rays_o[rayc*3+0], oy = rays_o[rayc*3+1], oz = rays_o[rayc*3+2];
    const float rdx = rays_d[rayc*3+0], rdy = rays_d[rayc*3+1], rdz = rays_d[rayc*3+2];
    const float rn = rsqrtf(rdx*rdx + rdy*rdy + rdz*rdz);
    const float dx = rdx*rn, dy = rdy*rn, dz = rdz*rn;

    const float ix = 1.0f/dx, iy = 1.0f/dy, iz = 1.0f/dz;
    const float t1x = (-1.f-ox)*ix, t2x = (1.f-ox)*ix;
    const float t1y = (-1.f-oy)*iy, t2y = (1.f-oy)*iy;
    const float t1z = (-1.f-oz)*iz, t2z = (1.f-oz)*iz;
    float nearv = fmaxf(fmaxf(fminf(t1x,t2x), fminf(t1y,t2y)), fminf(t1z,t2z));
    float farv  = fminf(fminf(fmaxf(t1x,t2x), fmaxf(t1y,t2y)), fmaxf(t1z,t2z));
    nearv = fmaxf(nearv, 0.2f);
    farv  = fmaxf(farv, nearv + 1e-6f);

    const float span    = farv - nearv;
    const float stepz   = (T > 1) ? span/(float)(T-1) : 0.f;
    const float inv_tm1 = (T > 1) ? 1.f/(float)(T-1) : 0.f;
    const float last_dt = span/(float)T;
    const float nStep2  = -stepz  * LOG2E;
    const float nLast2  = -last_dt * LOG2E;

    const u32 dirw0 = pkbf(dx, dy);
    const u32 dirw1 = pkbf(dz, 0.f);

    // segment bounds for this wave (8 segments over full T)
    const int Sper = (T + 7) >> 3;
    const int segStart = seg * Sper;
    const int segEnd = (segStart + Sper < T) ? (segStart + Sper) : T;
    const int nch = (segEnd > segStart) ? (segEnd - segStart) : 0;

    // per-lane constant LDS offsets (dwords)
    const int posOff = 4*c;                 // within tile: ray c -> c*PSTR
    const int stOff  = c*SSTR + g*4;        // within tile: ray c, rows g*4..+3

    float iA0=0.f,iA1=0.f,iA2=0.f,dAc=0.f,wsA=0.f,TAx=1.f;
    float iD0=0.f,iD1=0.f,iD2=0.f,dDc=0.f,wsD=0.f,TDx=1.f;
    const f32x4 z4 = {0.f,0.f,0.f,0.f};

    for (int cs = 0; cs < nch; ++cs) {
        const int tg = segStart + cs;

        // ---- phase A: own-ray B1 column for this sample -> posBuf ----
        {
            const float zv = fmaf(stepz, (float)tg, nearv);
            const float X = fminf(fmaxf(fmaf(dx, zv, ox), -1.f), 1.f);
            const float Y = fminf(fmaxf(fmaf(dy, zv, oy), -1.f), 1.f);
            const float Z = fminf(fmaxf(fmaf(dz, zv, oz), -1.f), 1.f);
            uint4 v;
            v.x = pktr(X, Y);
            v.y = pktr(Z, 1.0f);
            v.z = dirw0;
            v.w = dirw1;
            *(uint4*)&posW[lane*PSTR] = v;
        }

        // ---- phase B: 4 MFMA tiles (tile TAU = rays 16*TAU..16*TAU+15) ----
        __builtin_amdgcn_s_setprio(1);
#define TILEB(TAU)                                                                \
        {                                                                         \
            const uint4 b1u = *(const uint4*)&posW[(TAU)*(16*PSTR) + posOff];     \
            const bf16x8 b1f = __builtin_bit_cast(bf16x8, b1u);                   \
            f32x4 acc10 = __builtin_amdgcn_mfma_f32_16x16x32_bf16(                \
                __builtin_bit_cast(bf16x8, a1u0), b1f, z4, 0,0,0);                \
            f32x4 acc11 = __builtin_amdgcn_mfma_f32_16x16x32_bf16(                \
                __builtin_bit_cast(bf16x8, a1u1), b1f, z4, 0,0,0);                \
            f32x4 acc12 = __builtin_amdgcn_mfma_f32_16x16x32_bf16(                \
                __builtin_bit_cast(bf16x8, a1u2), b1f, z4, 0,0,0);                \
            f32x4 acc13 = __builtin_amdgcn_mfma_f32_16x16x32_bf16(                \
                __builtin_bit_cast(bf16x8, a1u3), b1f, z4, 0,0,0);                \
            const f32x4 r0 = __builtin_elementwise_max(acc10, z4);                \
            const f32x4 r1 = __builtin_elementwise_max(acc11, z4);                \
            const f32x4 r2 = __builtin_elementwise_max(acc12, z4);                \
            const f32x4 r3 = __builtin_elementwise_max(acc13, z4);                \
            uint4 b2a, b2b;                                                       \
            b2a.x = pktr(r0.x, r0.y);  b2a.y = pktr(r0.z, r0.w);                  \
            b2a.z = pktr(r1.x, r1.y);  b2a.w = pktr(r1.z, r1.w);                  \
            b2b.x = pktr(r2.x, r2.y);  b2b.y = pktr(r2.z, r2.w);                  \
            b2b.z = pktr(r3.x, r3.y);  b2b.w = pktr(r3.z, r3.w);                  \
            f32x4 acc2 = __builtin_amdgcn_mfma_f32_16x16x32_bf16(                 \
                __builtin_bit_cast(bf16x8, a2u0), __builtin_bit_cast(bf16x8, b2a),\
                z4, 0, 0, 0);                                                     \
            acc2 = __builtin_amdgcn_mfma_f32_16x16x32_bf16(                       \
                __builtin_bit_cast(bf16x8, a2u1), __builtin_bit_cast(bf16x8, b2b),\
                acc2, 0, 0, 0);                                                   \
            if (g < 2) {                                                          \
                *(f32x4*)&stashW[(TAU)*(16*SSTR) + stOff] = acc2;                 \
            }                                                                     \
        }
        TILEB(0) TILEB(1) TILEB(2) TILEB(3)
#undef TILEB
        __builtin_amdgcn_s_setprio(0);

        // ---- phase C: composite own ray's sample ----
        {
            const f32x4 oA = *(const f32x4*)&stashW[lane*SSTR];
            const f32x4 oB = *(const f32x4*)&stashW[lane*SSTR + 4];
            const float dneg2 = (tg < T-1) ? nStep2 : nLast2;
            const float z01   = (float)tg * inv_tm1;

            const float sigA = softplus_f(oA.x);
            const float qA = exp2f(dneg2*sigA);
            const float wA = TAx - TAx*qA; TAx *= qA;
            iA0 = fmaf(wA, sigmoid_f(oA.z), iA0);
            iA1 = fmaf(wA, sigmoid_f(oA.w), iA1);
            iA2 = fmaf(wA, sigmoid_f(oB.x), iA2);
            dAc = fmaf(wA, z01, dAc); wsA += wA;

            const float sigD = softplus_f(oA.y);
            const float qD = exp2f(dneg2*sigD);
            const float wD = TDx - TDx*qD; TDx *= qD;
            iD0 = fmaf(wD, sigmoid_f(oB.y), iD0);
            iD1 = fmaf(wD, sigmoid_f(oB.z), iD1);
            iD2 = fmaf(wD, sigmoid_f(oB.w), iD2);
            dDc = fmaf(wD, z01, dDc); wsD += wD;
        }
    }

    // ---- combine the 8 waves' segment states (comb aliases smem) ----
    __syncthreads();
    *(f32x4*)&comb[lane*CSTR + seg*12 + 0] = (f32x4){iA0, iA1, iA2, dAc};
    *(f32x4*)&comb[lane*CSTR + seg*12 + 4] = (f32x4){wsA, TAx, iD0, iD1};
    *(f32x4*)&comb[lane*CSTR + seg*12 + 8] = (f32x4){iD2, dDc, wsD, TDx};
    __syncthreads();

    if (seg == 0 && ray < N) {
        float tA = TAx, tD = TDx;
#pragma unroll
        for (int s = 1; s < 8; ++s) {
            const f32x4 v0 = *(const f32x4*)&comb[lane*CSTR + s*12 + 0];
            const f32x4 v1 = *(const f32x4*)&comb[lane*CSTR + s*12 + 4];
            const f32x4 v2 = *(const f32x4*)&comb[lane*CSTR + s*12 + 8];
            iA0 = fmaf(tA, v0.x, iA0);
            iA1 = fmaf(tA, v0.y, iA1);
            iA2 = fmaf(tA, v0.z, iA2);
            dAc = fmaf(tA, v0.w, dAc);
            wsA = fmaf(tA, v1.x, wsA);
            tA *= v1.y;
            iD0 = fmaf(tD, v1.z, iD0);
            iD1 = fmaf(tD, v1.w, iD1);
            iD2 = fmaf(tD, v2.x, iD2);
            dDc = fmaf(tD, v2.y, dDc);
            wsD = fmaf(tD, v2.z, wsD);
            tD *= v2.w;
        }
        const float bgA = 1.f - wsA;
        const float bgD = 1.f - wsD;
        float* o = out + (size_t)ray * 9;
        o[0] = iA0 + bgA;
        o[1] = iA1 + bgA;
        o[2] = iA2 + bgA;
        o[3] = dAc;
        o[4] = wsA;
        o[5] = iD0 + bgD;
        o[6] = iD1 + bgD;
        o[7] = iD2 + bgD;
        o[8] = dDc;
    }
}

extern "C" void kernel_launch(void* const* d_in, const int* in_sizes, int n_in,
                              void* d_out, int out_size, void* d_ws, size_t ws_size,
                              hipStream_t stream) {
    const float* rays_o = (const float*)d_in[0];
    const float* rays_d = (const float*)d_in[1];
    const float* W1     = (const float*)d_in[2];
    const float* b1     = (const float*)d_in[3];
    const float* Wsig   = (const float*)d_in[4];
    const float* Wsig_d = (const float*)d_in[5];
    const float* Wc1    = (const float*)d_in[6];
    const float* bc1    = (const float*)d_in[7];
    const float* Wc2    = (const float*)d_in[8];
    const float* Wc2_d  = (const float*)d_in[9];
    const int* num_steps = (const int*)d_in[10];

    const int N = in_sizes[0] / 3;
    float* out = (float*)d_out;
    u32*   ws  = (u32*)d_ws;    // 6 KB used

    hipLaunchKernelGGL(nerf_prep_kernel, dim3(1), dim3(256), 0, stream,
                       W1, b1, Wsig, Wsig_d, Wc1, bc1, Wc2, Wc2_d, ws);

    const int blocks = (N + 63) / 64;   // 64 rays per block (8 waves)
    hipLaunchKernelGGL(nerf_render_kernel, dim3(blocks), dim3(512), 0, stream,
                       rays_o, rays_d, ws, num_steps, out, N);
}

// Round 21
// 50.309 us; speedup vs baseline: 1.2700x; 1.0372x over previous
//
#include <hip/hip_runtime.h>
#include <hip/hip_bf16.h>

// NeRF surrogate renderer, MI355X — round 21: ping-pong LDS double-buffer.
// R20 (render 48.5us): no pipe saturated; remaining suspect is intra-chunk
// LDS WAR serialization (posBuf write -> tile reads -> stash write -> C reads,
// next chunk's posBuf write WAR-blocked on tile reads; ~3 fences x 120cyc x
// 16 chunks/wave). Fix: 2 slots/wave (8KB/wave, 64KB/block = WG limit),
// samples processed in pairs A0A1-B0B1-C0C1 -> fences overlap across slots.
// launch_bounds(512,4): <=128 VGPR for the ~80 live.

typedef float  f32x4  __attribute__((ext_vector_type(4)));
typedef short  bf16x8 __attribute__((ext_vector_type(8)));
typedef unsigned int u32;

__device__ __forceinline__ float fast_rcp(float x){ return __builtin_amdgcn_rcpf(x); }
__device__ __forceinline__ float softplus_f(float x){
    float e = __expf(-fabsf(x));
    return fmaxf(x,0.f) + __logf(1.f+e);
}
__device__ __forceinline__ float sigmoid_f(float x){ return fast_rcp(1.f+__expf(-x)); }

// truncation pack (1 op): (bf16(hi)<<16)|bf16(lo), RTZ
__device__ __forceinline__ u32 pktr(float lo, float hi){
    return __builtin_amdgcn_perm(__float_as_uint(hi), __float_as_uint(lo), 0x07060302u);
}
// exact RNE pack (cold paths)
__device__ __forceinline__ u32 bfr_hi(float f){
    u32 u = __float_as_uint(f);
    return (u + 0x7FFFu + ((u>>16)&1u)) & 0xFFFF0000u;
}
__device__ __forceinline__ u32 pkbf(float lo, float hi){
    return (bfr_hi(lo)>>16) | bfr_hi(hi);
}

// ---- prep: identical to R12-R20 (proven) ----
__global__ __launch_bounds__(256)
void nerf_prep_kernel(const float* __restrict__ W1, const float* __restrict__ b1,
                      const float* __restrict__ Wsig, const float* __restrict__ Wsig_d,
                      const float* __restrict__ Wc1, const float* __restrict__ bc1,
                      const float* __restrict__ Wc2, const float* __restrict__ Wc2_d,
                      u32* __restrict__ ws)
{
    const int q0 = threadIdx.x;
#pragma unroll
    for (int k = 0; k < 6; ++k) {
        const int q = q0 + k*256;
        u32 val = 0u;
        if (q < 1024) {
            const int ut = q>>8, rem = q&255, lane = rem>>2, dw = rem&3;
            const int g = lane>>4, m = lane&15;
            if (g == 0) {
                float w[8];
                if (ut < 2) { const int u = ut*16 + m;
                    w[0]=W1[u];  w[1]=W1[32+u];  w[2]=W1[64+u];  w[3]=b1[u];
                    w[4]=0.f;    w[5]=0.f;       w[6]=0.f;       w[7]=0.f;
                } else {        const int u = (ut-2)*16 + m;
                    w[0]=Wc1[u]; w[1]=Wc1[32+u]; w[2]=Wc1[64+u]; w[3]=bc1[u];
                    w[4]=Wc1[96+u]; w[5]=Wc1[128+u]; w[6]=Wc1[160+u]; w[7]=0.f;
                }
                val = pkbf(w[2*dw], w[2*dw+1]);
            }
        } else {
            const int q2 = q-1024, ch = q2>>8, rem = q2&255, lane = rem>>2, dw = rem&3;
            const int g = lane>>4, o = lane&15;
            float w[2];
#pragma unroll
            for (int e = 0; e < 2; ++e) {
                const int kk = 2*dw + e;
                const int h = kk>>2, rr = kk&3;
                const int u_local = h*16 + g*4 + rr;
                float v = 0.f;
                if (ch == 0) {
                    if (o == 0) v = Wsig[u_local];
                    else if (o == 1) v = Wsig_d[u_local];
                } else {
                    if (o >= 2 && o <= 4) v = Wc2[u_local*3 + (o-2)];
                    else if (o >= 5 && o <= 7) v = Wc2_d[u_local*3 + (o-5)];
                }
                w[e] = v;
            }
            val = pkbf(w[0], w[1]);
        }
        ws[q] = val;
    }
}

#define PSTR 4     // posBuf ray stride (dw): conflict-free
#define SSTR 12    // stash ray stride (dw): conflict-free
#define SLOT 1024  // dwords per slot: 64*PSTR + 64*SSTR
#define WSTR 2048  // per-wave LDS dwords (2 slots)
#define CSTR 100   // combine ray stride (dw)
#define LOG2E 1.44269504088896340736f

// ---- main: block = 8 waves = 64 rays x T samples (wave w = segment w) ----
__global__ __launch_bounds__(512, 4)
void nerf_render_kernel(const float* __restrict__ rays_o,
                        const float* __restrict__ rays_d,
                        const u32*  __restrict__ wsm,
                        const int*  __restrict__ num_steps,
                        float* __restrict__ out,
                        int N)
{
    __shared__ u32 smem[8 * WSTR];   // 65 536 B (WG limit)

    const int tid  = threadIdx.x;
    const int seg  = tid>>6, lane = tid&63;    // seg 0..7
    const int ray  = blockIdx.x*64 + lane;
    const int rayc = (ray < N) ? ray : (N-1);
    const int T = num_steps[0];
    const int g = lane>>4, c = lane&15;

    u32*   posW0   = smem + seg*WSTR;
    float* stash0  = (float*)(posW0 + 64*PSTR);
    u32*   posW1   = posW0 + SLOT;
    float* stash1  = (float*)(posW1 + 64*PSTR);
    float* comb    = (float*)smem;    // aliased; used only after barrier

    // weight fragments (proven layout), pinned
    const uint4* wsv = (const uint4*)wsm;
    uint4 a1u0 = wsv[0*64 + lane];
    uint4 a1u1 = wsv[1*64 + lane];
    uint4 a1u2 = wsv[2*64 + lane];
    uint4 a1u3 = wsv[3*64 + lane];
    uint4 a2u0 = wsv[256 + 0*64 + lane];
    uint4 a2u1 = wsv[256 + 1*64 + lane];
    asm volatile("" : "+v"(a1u0.x), "+v"(a1u0.y), "+v"(a1u0.z), "+v"(a1u0.w),
                      "+v"(a1u1.x), "+v"(a1u1.y), "+v"(a1u1.z), "+v"(a1u1.w),
                      "+v"(a1u2.x), "+v"(a1u2.y), "+v"(a1u2.z), "+v"(a1u2.w));
    asm volatile("" : "+v"(a1u3.x), "+v"(a1u3.y), "+v"(a1u3.z), "+v"(a1u3.w),
                      "+v"(a2u0.x), "+v"(a2u0.y), "+v"(a2u0.z), "+v"(a2u0.w),
                      "+v"(a2u1.x), "+v"(a2u1.y), "+v"(a2u1.z), "+v"(a2u1.w));

    // own-ray setup
    const float ox = rays_o[rayc*3+0], oy = rays_o[rayc*3+1], oz = rays_o[rayc*3+2];
    const float rdx = rays_d[rayc*3+0], rdy = rays_d[rayc*3+1], rdz = rays_d[rayc*3+2];
    const float rn = rsqrtf(rdx*rdx + rdy*rdy + rdz*rdz);
    const float dx = rdx*rn, dy = rdy*rn, dz = rdz*rn;

    const float ix = 1.0f/dx, iy = 1.0f/dy, iz = 1.0f/dz;
    const float t1x = (-1.f-ox)*ix, t2x = (1.f-ox)*ix;
    const float t1y = (-1.f-oy)*iy, t2y = (1.f-oy)*iy;
    const float t1z = (-1.f-oz)*iz, t2z = (1.f-oz)*iz;
    float nearv = fmaxf(fmaxf(fminf(t1x,t2x), fminf(t1y,t2y)), fminf(t1z,t2z));
    float farv  = fminf(fminf(fmaxf(t1x,t2x), fmaxf(t1y,t2y)), fmaxf(t1z,t2z));
    nearv = fmaxf(nearv, 0.2f);
    farv  = fmaxf(farv, nearv + 1e-6f);

    const float span    = farv - nearv;
    const float stepz   = (T > 1) ? span/(float)(T-1) : 0.f;
    const float inv_tm1 = (T > 1) ? 1.f/(float)(T-1) : 0.f;
    const float last_dt = span/(float)T;
    const float nStep2  = -stepz  * LOG2E;
    const float nLast2  = -last_dt * LOG2E;

    const u32 dirw0 = pkbf(dx, dy);
    const u32 dirw1 = pkbf(dz, 0.f);

    // segment bounds for this wave (8 segments over full T)
    const int Sper = (T + 7) >> 3;
    const int segStart = seg * Sper;
    const int segEnd = (segStart + Sper < T) ? (segStart + Sper) : T;
    const int nch = (segEnd > segStart) ? (segEnd - segStart) : 0;

    // per-lane constant LDS offsets (dwords)
    const int posOff = 4*c;
    const int stOff  = c*SSTR + g*4;

    float iA0=0.f,iA1=0.f,iA2=0.f,dAc=0.f,wsA=0.f,TAx=1.f;
    float iD0=0.f,iD1=0.f,iD2=0.f,dDc=0.f,wsD=0.f,TDx=1.f;
    const f32x4 z4 = {0.f,0.f,0.f,0.f};

#define PHASEA(TG, PW)                                                            \
    {                                                                             \
        const float zv = fmaf(stepz, (float)(TG), nearv);                         \
        const float X = fminf(fmaxf(fmaf(dx, zv, ox), -1.f), 1.f);                \
        const float Y = fminf(fmaxf(fmaf(dy, zv, oy), -1.f), 1.f);                \
        const float Z = fminf(fmaxf(fmaf(dz, zv, oz), -1.f), 1.f);                \
        uint4 v;                                                                  \
        v.x = pktr(X, Y);                                                         \
        v.y = pktr(Z, 1.0f);                                                      \
        v.z = dirw0;                                                              \
        v.w = dirw1;                                                              \
        *(uint4*)&(PW)[lane*PSTR] = v;                                            \
    }

#define TILEB(TAU, PW, SW)                                                        \
    {                                                                             \
        const uint4 b1u = *(const uint4*)&(PW)[(TAU)*(16*PSTR) + posOff];         \
        const bf16x8 b1f = __builtin_bit_cast(bf16x8, b1u);                       \
        f32x4 acc10 = __builtin_amdgcn_mfma_f32_16x16x32_bf16(                    \
            __builtin_bit_cast(bf16x8, a1u0), b1f, z4, 0,0,0);                    \
        f32x4 acc11 = __builtin_amdgcn_mfma_f32_16x16x32_bf16(                    \
            __builtin_bit_cast(bf16x8, a1u1), b1f, z4, 0,0,0);                    \
        f32x4 acc12 = __builtin_amdgcn_mfma_f32_16x16x32_bf16(                    \
            __builtin_bit_cast(bf16x8, a1u2), b1f, z4, 0,0,0);                    \
        f32x4 acc13 = __builtin_amdgcn_mfma_f32_16x16x32_bf16(                    \
            __builtin_bit_cast(bf16x8, a1u3), b1f, z4, 0,0,0);                    \
        const f32x4 r0 = __builtin_elementwise_max(acc10, z4);                    \
        const f32x4 r1 = __builtin_elementwise_max(acc11, z4);                    \
        const f32x4 r2 = __builtin_elementwise_max(acc12, z4);                    \
        const f32x4 r3 = __builtin_elementwise_max(acc13, z4);                    \
        uint4 b2a, b2b;                                                           \
        b2a.x = pktr(r0.x, r0.y);  b2a.y = pktr(r0.z, r0.w);                      \
        b2a.z = pktr(r1.x, r1.y);  b2a.w = pktr(r1.z, r1.w);                      \
        b2b.x = pktr(r2.x, r2.y);  b2b.y = pktr(r2.z, r2.w);                      \
        b2b.z = pktr(r3.x, r3.y);  b2b.w = pktr(r3.z, r3.w);                      \
        f32x4 acc2 = __builtin_amdgcn_mfma_f32_16x16x32_bf16(                     \
            __builtin_bit_cast(bf16x8, a2u0), __builtin_bit_cast(bf16x8, b2a),    \
            z4, 0, 0, 0);                                                         \
        acc2 = __builtin_amdgcn_mfma_f32_16x16x32_bf16(                           \
            __builtin_bit_cast(bf16x8, a2u1), __builtin_bit_cast(bf16x8, b2b),    \
            acc2, 0, 0, 0);                                                       \
        if (g < 2) {                                                              \
            *(f32x4*)&(SW)[(TAU)*(16*SSTR) + stOff] = acc2;                       \
        }                                                                         \
    }

#define PHASEC(TG, SW)                                                            \
    {                                                                             \
        const f32x4 oA = *(const f32x4*)&(SW)[lane*SSTR];                         \
        const f32x4 oB = *(const f32x4*)&(SW)[lane*SSTR + 4];                     \
        const float dneg2 = ((TG) < T-1) ? nStep2 : nLast2;                       \
        const float z01   = (float)(TG) * inv_tm1;                                \
        const float sigA = softplus_f(oA.x);                                      \
        const float qA = exp2f(dneg2*sigA);                                       \
        const float wA = TAx - TAx*qA; TAx *= qA;                                 \
        iA0 = fmaf(wA, sigmoid_f(oA.z), iA0);                                     \
        iA1 = fmaf(wA, sigmoid_f(oA.w), iA1);                                     \
        iA2 = fmaf(wA, sigmoid_f(oB.x), iA2);                                     \
        dAc = fmaf(wA, z01, dAc); wsA += wA;                                      \
        const float sigD = softplus_f(oA.y);                                      \
        const float qD = exp2f(dneg2*sigD);                                       \
        const float wD = TDx - TDx*qD; TDx *= qD;                                 \
        iD0 = fmaf(wD, sigmoid_f(oB.y), iD0);                                     \
        iD1 = fmaf(wD, sigmoid_f(oB.z), iD1);                                     \
        iD2 = fmaf(wD, sigmoid_f(oB.w), iD2);                                     \
        dDc = fmaf(wD, z01, dDc); wsD += wD;                                      \
    }

    for (int cs = 0; cs < nch; cs += 2) {
        const int tg0 = segStart + cs;
        const int tg1 = tg0 + 1;
        const bool has2 = (cs + 1 < nch);

        // phase A both slots (slot1's write is independent of slot0's readers)
        PHASEA(tg0, posW0)
        if (has2) PHASEA(tg1, posW1)

        // phase B both slots, MFMA-priority
        __builtin_amdgcn_s_setprio(1);
        TILEB(0, posW0, stash0) TILEB(1, posW0, stash0)
        TILEB(2, posW0, stash0) TILEB(3, posW0, stash0)
        if (has2) {
            TILEB(0, posW1, stash1) TILEB(1, posW1, stash1)
            TILEB(2, posW1, stash1) TILEB(3, posW1, stash1)
        }
        __builtin_amdgcn_s_setprio(0);

        // phase C sequential (composite order preserved)
        PHASEC(tg0, stash0)
        if (has2) PHASEC(tg1, stash1)
    }
#undef PHASEA
#undef TILEB
#undef PHASEC

    // ---- combine the 8 waves' segment states (comb aliases smem) ----
    __syncthreads();
    *(f32x4*)&comb[lane*CSTR + seg*12 + 0] = (f32x4){iA0, iA1, iA2, dAc};
    *(f32x4*)&comb[lane*CSTR + seg*12 + 4] = (f32x4){wsA, TAx, iD0, iD1};
    *(f32x4*)&comb[lane*CSTR + seg*12 + 8] = (f32x4){iD2, dDc, wsD, TDx};
    __syncthreads();

    if (seg == 0 && ray < N) {
        float tA = TAx, tD = TDx;
#pragma unroll
        for (int s = 1; s < 8; ++s) {
            const f32x4 v0 = *(const f32x4*)&comb[lane*CSTR + s*12 + 0];
            const f32x4 v1 = *(const f32x4*)&comb[lane*CSTR + s*12 + 4];
            const f32x4 v2 = *(const f32x4*)&comb[lane*CSTR + s*12 + 8];
            iA0 = fmaf(tA, v0.x, iA0);
            iA1 = fmaf(tA, v0.y, iA1);
            iA2 = fmaf(tA, v0.z, iA2);
            dAc = fmaf(tA, v0.w, dAc);
            wsA = fmaf(tA, v1.x, wsA);
            tA *= v1.y;
            iD0 = fmaf(tD, v1.z, iD0);
            iD1 = fmaf(tD, v1.w, iD1);
            iD2 = fmaf(tD, v2.x, iD2);
            dDc = fmaf(tD, v2.y, dDc);
            wsD = fmaf(tD, v2.z, wsD);
            tD *= v2.w;
        }
        const float bgA = 1.f - wsA;
        const float bgD = 1.f - wsD;
        float* o = out + (size_t)ray * 9;
        o[0] = iA0 + bgA;
        o[1] = iA1 + bgA;
        o[2] = iA2 + bgA;
        o[3] = dAc;
        o[4] = wsA;
        o[5] = iD0 + bgD;
        o[6] = iD1 + bgD;
        o[7] = iD2 + bgD;
        o[8] = dDc;
    }
}

extern "C" void kernel_launch(void* const* d_in, const int* in_sizes, int n_in,
                              void* d_out, int out_size, void* d_ws, size_t ws_size,
                              hipStream_t stream) {
    const float* rays_o = (const float*)d_in[0];
    const float* rays_d = (const float*)d_in[1];
    const float* W1     = (const float*)d_in[2];
    const float* b1     = (const float*)d_in[3];
    const float* Wsig   = (const float*)d_in[4];
    const float* Wsig_d = (const float*)d_in[5];
    const float* Wc1    = (const float*)d_in[6];
    const float* bc1    = (const float*)d_in[7];
    const float* Wc2    = (const float*)d_in[8];
    const float* Wc2_d  = (const float*)d_in[9];
    const int* num_steps = (const int*)d_in[10];

    const int N = in_sizes[0] / 3;
    float* out = (float*)d_out;
    u32*   ws  = (u32*)d_ws;    // 6 KB used

    hipLaunchKernelGGL(nerf_prep_kernel, dim3(1), dim3(256), 0, stream,
                       W1, b1, Wsig, Wsig_d, Wc1, bc1, Wc2, Wc2_d, ws);

    const int blocks = (N + 63) / 64;   // 64 rays per block (8 waves)
    hipLaunchKernelGGL(nerf_render_kernel, dim3(blocks), dim3(512), 0, stream,
                       rays_o, rays_d, ws, num_steps, out, N);
}